// Round 7
// baseline (654.020 us; speedup 1.0000x reference)
//
#include <hip/hip_runtime.h>
#include <cstdint>

typedef unsigned short u16;
typedef short s16x8 __attribute__((ext_vector_type(8)));
typedef float f32x4 __attribute__((ext_vector_type(4)));
typedef float f32x16 __attribute__((ext_vector_type(16)));

#if __has_builtin(__builtin_amdgcn_exp2f)
#define EXP2(x) __builtin_amdgcn_exp2f(x)
#else
#define EXP2(x) __expf((x)*0.6931471805599453f)
#endif

__device__ __forceinline__ u16 f2bf(float x) {
  uint32_t u = __builtin_bit_cast(uint32_t, x);
  u += 0x7FFFu + ((u >> 16) & 1u);   // RTNE
  return (u16)(u >> 16);
}
__device__ __forceinline__ float bf2f(u16 v) {
  return __builtin_bit_cast(float, (uint32_t)v << 16);
}
__device__ __forceinline__ uint32_t pk_bf16(float lo, float hi) {
  uint32_t ul = __builtin_bit_cast(uint32_t, lo);
  uint32_t uh = __builtin_bit_cast(uint32_t, hi);
  ul += 0x7FFFu + ((ul >> 16) & 1u);
  uh += 0x7FFFu + ((uh >> 16) & 1u);
  return __builtin_amdgcn_perm(uh, ul, 0x07060302u);
}
__device__ __forceinline__ f32x4 mfma16(s16x8 a, s16x8 b, f32x4 c) {
  return __builtin_amdgcn_mfma_f32_16x16x32_bf16(a, b, c, 0, 0, 0);
}
__device__ __forceinline__ f32x16 mfma32(s16x8 a, s16x8 b, f32x16 c) {
  return __builtin_amdgcn_mfma_f32_32x32x16_bf16(a, b, c, 0, 0, 0);
}
__device__ __forceinline__ s16x8 ld_frag(const u16* p) {
  uint4 v = *(const uint4*)p;
  return __builtin_bit_cast(s16x8, v);
}

// ---------------- kernel 1: W fp32 -> bf16, MFMA-fragment-linear order -----
// Q scale = 1/sqrt(32) * log2(e)  (exp -> exp2 fold, see attn)
__global__ void prep_w(const float* __restrict__ Wq, const float* __restrict__ Wkv,
                       u16* __restrict__ wqs, u16* __restrict__ wkvs) {
  int tid = blockIdx.x * 256 + threadIdx.x;        // 0 .. 13823
  if (tid >= 13824) return;
  bool isQ = tid < 4608;                           // Q: 12 fb * 6 kk * 64 lanes
  int id = isQ ? tid : tid - 4608;                 // KV: 24 fb * 6 kk * 64 lanes
  int lane = id & 63, fk = id >> 6;
  int kk = fk % 6, fb = fk / 6;
  int f = fb * 16 + (lane & 15), k0 = kk * 32 + ((lane >> 4) << 3);
  const float* src = (isQ ? Wq : Wkv) + (size_t)f * 192 + k0;
  const float sc = isQ ? 0.2550348583f : 1.0f;     // (1/sqrt(32))*log2e
  float4 a = ((const float4*)src)[0], b = ((const float4*)src)[1];
  uint4 o;
  o.x = pk_bf16(a.x * sc, a.y * sc); o.y = pk_bf16(a.z * sc, a.w * sc);
  o.z = pk_bf16(b.x * sc, b.y * sc); o.w = pk_bf16(b.z * sc, b.w * sc);
  *(uint4*)&(isQ ? wqs : wkvs)[(size_t)id * 8] = o;
}

// ---------------- kernel 2: rpb in MFMA-C fragment order -------------------
// rpb4[h][kt][w][lane][r] = bf16(log2e * table[rpi[q][key]][h])
//   q = w*32 + (lane&31), key = kt*32 + (r&3) + 8*(r>>2) + 4*(lane>>5)
__global__ void build_rpb(const int* __restrict__ rpi, const float* __restrict__ table,
                          u16* __restrict__ rpb) {
  const int bi = blockIdx.x;                       // grid 108 = 6h * 18kt
  const int h = bi / 18, kt = bi - h * 18;
  const int t = threadIdx.x, lane = t & 63, w = t >> 6;
  const int u = lane >> 5, l31 = lane & 31;
  const int q = (w << 5) + l31;
  const int n0 = (kt << 5) + (u << 2);             // + 8g gives the int4 base
  u16 vals[16];
#pragma unroll
  for (int g = 0; g < 4; ++g) {
    int4 id4 = *(const int4*)&rpi[q * 576 + n0 + (g << 3)];   // keys +0..3
    vals[(g << 2) + 0] = f2bf(table[id4.x * 6 + h] * 1.4426950409f);
    vals[(g << 2) + 1] = f2bf(table[id4.y * 6 + h] * 1.4426950409f);
    vals[(g << 2) + 2] = f2bf(table[id4.z * 6 + h] * 1.4426950409f);
    vals[(g << 2) + 3] = f2bf(table[id4.w * 6 + h] * 1.4426950409f);
  }
  uint4* dst = (uint4*)&rpb[((size_t)bi * 512 + t) * 16];
  dst[0] = *(uint4*)&vals[0];
  dst[1] = *(uint4*)&vals[8];
}

// ---------------- kernel 3: W-STATIONARY projection GEMM -------------------
// R6: each wave owns G fb-columns (Q:3, KV:6) with its W slice RESIDENT in
// registers (loaded once, reused over 8 M-tiles). A staged block-shared into
// a 3-slot LDS ring: loads for tile i+2 issued at tile i (2-tile latency
// cover), ds_write deferred one tile, one barrier/tile. Inner loop has ZERO
// global loads -> removes the serial W-load stream that pinned MfmaUtil at
// ~8.5% across R2/R4/R5 regardless of prefetch depth or barriers.
template <int G, int MODE>
__device__ __forceinline__ void proj_body(const float* __restrict__ A,
                                          const u16* __restrict__ W,
                                          u16* __restrict__ outQ, u16* __restrict__ outK,
                                          u16* __restrict__ outV, int blk0,
                                          u16* __restrict__ lds) {
  const int t = threadIdx.x, lane = t & 63, w = t >> 6, c = lane & 15, hi = lane >> 4;
  // ---- resident W slice: fb-frags w*G .. w*G+G-1, all 6 kk ----
  s16x8 wf[G][6];
#pragma unroll
  for (int f = 0; f < G; ++f)
#pragma unroll
    for (int kk = 0; kk < 6; ++kk)
      wf[f][kk] = ld_frag(&W[((size_t)(((w * G + f) * 6 + kk) * 64 + lane)) * 8]);
  // ---- staging geometry: thread covers row t>>4, 12 cols at (t&15)*12 ----
  const int srow = t >> 4, scol = (t & 15) * 12;
  float4 r0, r1, r2;
  auto ISSUE = [&](int i) {
    const float* src = A + (size_t)((blk0 * 8 + i) * 16 + srow) * 192 + scol;
    r0 = ((const float4*)src)[0];
    r1 = ((const float4*)src)[1];
    r2 = ((const float4*)src)[2];
  };
  auto WRITE = [&](int slot) {
    u16* sl = lds + slot * 3072;
#pragma unroll
    for (int j = 0; j < 3; ++j) {
      float4 v = (j == 0) ? r0 : (j == 1) ? r1 : r2;
      const int c0 = scol + j * 4, kk = c0 >> 5, rem = c0 & 31;
      const int h2 = rem >> 3, e0 = rem & 7;
      uint2 pv;
      pv.x = pk_bf16(v.x, v.y);
      pv.y = pk_bf16(v.z, v.w);
      *(uint2*)&sl[((kk << 6) + (h2 << 4) + srow) * 8 + e0] = pv;
    }
  };
  ISSUE(0); WRITE(0);                              // one-time stall, slot0
  ISSUE(1);                                        // tile1 in flight
  for (int i = 0; i < 8; ++i) {
    __syncthreads();                               // slot i%3 ready for all
    if (i + 1 < 8) WRITE((i + 1) % 3);             // regs from iter i-1: landed
    if (i + 2 < 8) ISSUE(i + 2);                   // 2-tile cover
    const u16* sl = lds + (i % 3) * 3072;
    s16x8 af[6];
#pragma unroll
    for (int kk = 0; kk < 6; ++kk)
      af[kk] = ld_frag(&sl[((kk << 6) + lane) << 3]);
    f32x4 acc[G];
#pragma unroll
    for (int f = 0; f < G; ++f) acc[f] = f32x4{0.f, 0.f, 0.f, 0.f};
#pragma unroll
    for (int kk = 0; kk < 6; ++kk)
#pragma unroll
      for (int f = 0; f < G; ++f)
        acc[f] = mfma16(wf[f][kk], af[kk], acc[f]);
    const int m = (blk0 * 8 + i) * 16 + c;
#pragma unroll
    for (int f = 0; f < G; ++f) {
      const int fb = ((w * G + f) << 4) + (hi << 2);
      uint2 pv;
      pv.x = pk_bf16(acc[f][0], acc[f][1]);
      pv.y = pk_bf16(acc[f][2], acc[f][3]);
      if (MODE == 0) {
        int b = m >> 8, q = m & 255, hh = fb >> 5, d = fb & 31;
        *(uint2*)&outQ[((((size_t)(b * 6 + hh)) << 8) + q) * 32 + d] = pv;
      } else {
        int b = m / 576, tok = m - b * 576;
        if (fb >= 192) {                           // V: layout unchanged
          int f2 = fb - 192, hh = f2 >> 5, d = f2 & 31;
          *(uint2*)&outV[(((size_t)(b * 6 + hh)) * 576 + tok) * 32 + d] = pv;
        } else {                                   // K: fragment-linear for attn
          int hh = fb >> 5, dd = fb & 31;
          int half = dd >> 4, uu = (dd >> 3) & 1, e0 = dd & 7;
          int ktt = tok >> 5, lt = tok & 31;
          *(uint2*)&outK[(size_t)((b * 6 + hh) * 18 + ktt) * 1024 +
                         half * 512 + uu * 256 + lt * 8 + e0] = pv;
        }
      }
    }
  }
}

__launch_bounds__(256, 2)
__global__ void proj_all(const float* __restrict__ xq, const float* __restrict__ xkv,
                         const u16* __restrict__ wqs, const u16* __restrict__ wkvs,
                         u16* __restrict__ Qws, u16* __restrict__ Kws,
                         u16* __restrict__ Vws) {
  __shared__ __align__(16) u16 lds[9216];          // 18,432 B: 3-slot A ring
  int blk = blockIdx.x;
  if (blk < 512) proj_body<3, 0>(xq, wqs, Qws, nullptr, nullptr, blk, lds);
  else           proj_body<6, 1>(xkv, wkvs, nullptr, Kws, Vws, blk - 512, lds);
}

// ---------------- kernel 4: fused attention, depth-4 K/bias pipeline -------
// R6: K + bias register-prefetched 4 kt ahead (cover ~570 cy vs ~500 cy L3
// latency; depth-2's 284 cy was the stall R2 counters showed as VALUBusy 37%).
// Full unroll keeps ring indices compile-time. Math identical (verified).
#define VSTR 600
__launch_bounds__(512)
__global__ void attn(const u16* __restrict__ Qws, const u16* __restrict__ Kws,
                     const u16* __restrict__ Vws, const u16* __restrict__ rpb,
                     float* __restrict__ out) {
  __shared__ __align__(16) u16 Vt[32 * VSTR];
  const int bh = blockIdx.x, b = bh / 6, h = bh - b * 6;
  const size_t kvbase = (size_t)bh * 576 * 32;     // V only
  const int t = threadIdx.x;
  for (int key = t; key < 576; key += 512) {       // stage V permuted (verified)
    int kk = key & 31, k15 = kk & 15;
    int p = ((kk >> 4) << 4) | (((k15 >> 2) & 1) << 3) | ((k15 >> 3) << 2) | (k15 & 3);
    int col = ((key >> 5) << 5) + p;
    const uint4* src = (const uint4*)&Vws[kvbase + (size_t)key * 32];
    uint4 r[4] = {src[0], src[1], src[2], src[3]};
    const u16* vs = (const u16*)r;
#pragma unroll
    for (int d = 0; d < 32; ++d) Vt[d * VSTR + col] = vs[d];
  }
  const int lane = t & 63, l31 = lane & 31, u = lane >> 5, w = t >> 6;
  const int qg = (w << 5) + l31;
  s16x8 qf[2];
#pragma unroll
  for (int m = 0; m < 2; ++m)
    qf[m] = ld_frag(&Qws[((size_t)bh * 256 + qg) * 32 + (m << 4) + (u << 3)]);
  __syncthreads();
  f32x16 oacc;
#pragma unroll
  for (int r = 0; r < 16; ++r) oacc[r] = 0.f;
  float psum = 0.f;
  // K fragment-linear: per kt, kA at kfb + kt*1024, kB at +512 (u16 units)
  const u16* kfb = Kws + (size_t)bh * 18432 + (size_t)lane * 8;
  // bias fragment-linear: per kt, 16 u16 at bp0 + kt*8192
  const u16* bp0 = rpb + (size_t)h * 147456 + (size_t)t * 16;
  s16x8 kA[4], kB[4];
  uint4 bA[4], bB[4];
#pragma unroll
  for (int s = 0; s < 4; ++s) {
    kA[s] = ld_frag(kfb + (size_t)s * 1024);
    kB[s] = ld_frag(kfb + (size_t)s * 1024 + 512);
    bA[s] = *(const uint4*)(bp0 + (size_t)s * 8192);
    bB[s] = *(const uint4*)(bp0 + (size_t)s * 8192 + 8);
  }
#pragma unroll
  for (int kt = 0; kt < 18; ++kt) {
    const int k0 = kt << 5, cur = kt & 3;          // compile-time (full unroll)
    s16x8 vf0 = ld_frag(&Vt[l31 * VSTR + k0 + (u << 3)]);
    s16x8 vf1 = ld_frag(&Vt[l31 * VSTR + k0 + 16 + (u << 3)]);
    f32x16 st;
#pragma unroll
    for (int r = 0; r < 16; ++r) st[r] = 0.f;
    st = mfma32(kA[cur], qf[0], st);               // d = 0..15
    st = mfma32(kB[cur], qf[1], st);               // d = 16..31
    uint4 bAc = bA[cur], bBc = bB[cur];
    if (kt < 14) {                                 // prefetch kt+4
      kA[cur] = ld_frag(kfb + (size_t)(kt + 4) * 1024);
      kB[cur] = ld_frag(kfb + (size_t)(kt + 4) * 1024 + 512);
      bA[cur] = *(const uint4*)(bp0 + (size_t)(kt + 4) * 8192);
      bB[cur] = *(const uint4*)(bp0 + (size_t)(kt + 4) * 8192 + 8);
    }
    const u16* b0 = (const u16*)&bAc;
    const u16* b1 = (const u16*)&bBc;
    float e[16];
#pragma unroll
    for (int r = 0; r < 8; ++r)
      e[r] = EXP2(st[r] + bf2f(b0[r]));            // key-row = (r&3)+8(r>>2)+4u
#pragma unroll
    for (int r = 8; r < 16; ++r)
      e[r] = EXP2(st[r] + bf2f(b1[r - 8]));
    psum += (((e[0] + e[1]) + (e[2] + e[3])) + ((e[4] + e[5]) + (e[6] + e[7]))) +
            (((e[8] + e[9]) + (e[10] + e[11])) + ((e[12] + e[13]) + (e[14] + e[15])));
    uint4 pa, pb;
    pa.x = pk_bf16(e[0], e[1]);   pa.y = pk_bf16(e[2], e[3]);
    pa.z = pk_bf16(e[4], e[5]);   pa.w = pk_bf16(e[6], e[7]);
    pb.x = pk_bf16(e[8], e[9]);   pb.y = pk_bf16(e[10], e[11]);
    pb.z = pk_bf16(e[12], e[13]); pb.w = pk_bf16(e[14], e[15]);
    s16x8 pf0 = __builtin_bit_cast(s16x8, pa);
    s16x8 pf1 = __builtin_bit_cast(s16x8, pb);
    oacc = mfma32(vf0, pf0, oacc);
    oacc = mfma32(vf1, pf1, oacc);
  }
  float tot = psum + __shfl_xor(psum, 32);
  float rs = 1.0f / tot;
  float* op = out + ((size_t)b * 256 + qg) * 192 + h * 32 + (u << 2);
#pragma unroll
  for (int g = 0; g < 4; ++g) {
    float4 o;
    o.x = oacc[(g << 2) + 0] * rs; o.y = oacc[(g << 2) + 1] * rs;
    o.z = oacc[(g << 2) + 2] * rs; o.w = oacc[(g << 2) + 3] * rs;
    *(float4*)(op + (g << 3)) = o;
  }
}

// ---------------- launcher -------------------------------------------------
extern "C" void kernel_launch(void* const* d_in, const int* in_sizes, int n_in,
                              void* d_out, int out_size, void* d_ws, size_t ws_size,
                              hipStream_t stream) {
  const float* x_q   = (const float*)d_in[0];
  const float* x_kv  = (const float*)d_in[1];
  const int*   rpi   = (const int*)d_in[2];
  const float* Wq    = (const float*)d_in[3];
  const float* Wkv   = (const float*)d_in[4];
  const float* table = (const float*)d_in[5];
  float* out = (float*)d_out;

  char* ws = (char*)d_ws;
  u16* wqs  = (u16*)(ws);                          //    73,728 B (swizzled)
  u16* wkvs = (u16*)(ws + 73728);                  //   147,456 B (swizzled)
  u16* rpb  = (u16*)(ws + 221184);                 // 1,769,472 B  frag-order
  u16* Qws  = (u16*)(ws + 1990656);                // 25,165,824 B
  u16* Kws  = (u16*)(ws + 27156480);               // 56,623,104 B (frag-linear)
  u16* Vws  = (u16*)(ws + 83779584);               // 56,623,104 B  (total ~134 MB)

  prep_w<<<54, 256, 0, stream>>>(Wq, Wkv, wqs, wkvs);
  build_rpb<<<108, 512, 0, stream>>>(rpi, table, rpb);
  proj_all<<<1664, 256, 0, stream>>>(x_q, x_kv, wqs, wkvs, Qws, Kws, Vws);
  attn<<<1536, 512, 0, stream>>>(Qws, Kws, Vws, rpb, out);
}

// Round 8
// 337.227 us; speedup vs baseline: 1.9394x; 1.9394x over previous
//
#include <hip/hip_runtime.h>
#include <cstdint>

typedef unsigned short u16;
typedef short s16x8 __attribute__((ext_vector_type(8)));
typedef float f32x4 __attribute__((ext_vector_type(4)));
typedef float f32x16 __attribute__((ext_vector_type(16)));

#if __has_builtin(__builtin_amdgcn_exp2f)
#define EXP2(x) __builtin_amdgcn_exp2f(x)
#else
#define EXP2(x) __expf((x)*0.6931471805599453f)
#endif

__device__ __forceinline__ u16 f2bf(float x) {
  uint32_t u = __builtin_bit_cast(uint32_t, x);
  u += 0x7FFFu + ((u >> 16) & 1u);   // RTNE
  return (u16)(u >> 16);
}
__device__ __forceinline__ float bf2f(u16 v) {
  return __builtin_bit_cast(float, (uint32_t)v << 16);
}
__device__ __forceinline__ uint32_t pk_bf16(float lo, float hi) {
  uint32_t ul = __builtin_bit_cast(uint32_t, lo);
  uint32_t uh = __builtin_bit_cast(uint32_t, hi);
  ul += 0x7FFFu + ((ul >> 16) & 1u);
  uh += 0x7FFFu + ((uh >> 16) & 1u);
  return __builtin_amdgcn_perm(uh, ul, 0x07060302u);
}
__device__ __forceinline__ f32x4 mfma16(s16x8 a, s16x8 b, f32x4 c) {
  return __builtin_amdgcn_mfma_f32_16x16x32_bf16(a, b, c, 0, 0, 0);
}
__device__ __forceinline__ f32x16 mfma32(s16x8 a, s16x8 b, f32x16 c) {
  return __builtin_amdgcn_mfma_f32_32x32x16_bf16(a, b, c, 0, 0, 0);
}
__device__ __forceinline__ s16x8 ld_frag(const u16* p) {
  uint4 v = *(const uint4*)p;
  return __builtin_bit_cast(s16x8, v);
}

// ---------------- kernel 1: W fp32 -> bf16, MFMA-fragment-linear order -----
// Q scale = 1/sqrt(32) * log2(e)  (exp -> exp2 fold, see attn)
__global__ void prep_w(const float* __restrict__ Wq, const float* __restrict__ Wkv,
                       u16* __restrict__ wqs, u16* __restrict__ wkvs) {
  int tid = blockIdx.x * 256 + threadIdx.x;        // 0 .. 13823
  if (tid >= 13824) return;
  bool isQ = tid < 4608;                           // Q: 12 fb * 6 kk * 64 lanes
  int id = isQ ? tid : tid - 4608;                 // KV: 24 fb * 6 kk * 64 lanes
  int lane = id & 63, fk = id >> 6;
  int kk = fk % 6, fb = fk / 6;
  int f = fb * 16 + (lane & 15), k0 = kk * 32 + ((lane >> 4) << 3);
  const float* src = (isQ ? Wq : Wkv) + (size_t)f * 192 + k0;
  const float sc = isQ ? 0.2550348583f : 1.0f;     // (1/sqrt(32))*log2e
  float4 a = ((const float4*)src)[0], b = ((const float4*)src)[1];
  uint4 o;
  o.x = pk_bf16(a.x * sc, a.y * sc); o.y = pk_bf16(a.z * sc, a.w * sc);
  o.z = pk_bf16(b.x * sc, b.y * sc); o.w = pk_bf16(b.z * sc, b.w * sc);
  *(uint4*)&(isQ ? wqs : wkvs)[(size_t)id * 8] = o;
}

// ---------------- kernel 2: rpb in MFMA-C fragment order -------------------
// rpb4[h][kt][w][lane][r] = bf16(log2e * table[rpi[q][key]][h])
//   q = w*32 + (lane&31), key = kt*32 + (r&3) + 8*(r>>2) + 4*(lane>>5)
// R8: grid 108 -> 864 (block 64). The 108-block version left the GPU ~99%
// idle (216 waves / 1024 SIMDs) on a scatter-gather => ~100 us hidden cost
// (accounting: R5 total 361 - proj 124 - attn <124 - prep ~5 => rpb ~110).
// Identical bytes written, 8x the waves in flight.
__global__ void build_rpb(const int* __restrict__ rpi, const float* __restrict__ table,
                          u16* __restrict__ rpb) {
  const int bi = blockIdx.x;                       // grid 864 = (6h*18kt) * 8w
  const int wv = bi & 7, hk = bi >> 3;
  const int h = hk / 18, kt = hk - h * 18;
  const int lane = threadIdx.x;                    // block 64
  const int u = lane >> 5, l31 = lane & 31;
  const int q = (wv << 5) + l31;
  const int n0 = (kt << 5) + (u << 2);             // + 8g gives the int4 base
  u16 vals[16];
#pragma unroll
  for (int g = 0; g < 4; ++g) {
    int4 id4 = *(const int4*)&rpi[q * 576 + n0 + (g << 3)];   // keys +0..3
    vals[(g << 2) + 0] = f2bf(table[id4.x * 6 + h] * 1.4426950409f);
    vals[(g << 2) + 1] = f2bf(table[id4.y * 6 + h] * 1.4426950409f);
    vals[(g << 2) + 2] = f2bf(table[id4.z * 6 + h] * 1.4426950409f);
    vals[(g << 2) + 3] = f2bf(table[id4.w * 6 + h] * 1.4426950409f);
  }
  uint4* dst = (uint4*)&rpb[((size_t)hk * 512 + (wv << 6) + lane) * 16];
  dst[0] = *(uint4*)&vals[0];
  dst[1] = *(uint4*)&vals[8];
}

// ---------------- kernel 3: W-STATIONARY projection GEMM -------------------
// Each wave owns G fb-columns (Q:3, KV:6) with its W slice RESIDENT in
// registers (loaded once, reused over 8 M-tiles). A staged block-shared into
// a 3-slot LDS ring: loads for tile i+2 issued at tile i, ds_write deferred
// one tile, one barrier/tile. Inner loop has ZERO global loads.
template <int G, int MODE>
__device__ __forceinline__ void proj_body(const float* __restrict__ A,
                                          const u16* __restrict__ W,
                                          u16* __restrict__ outQ, u16* __restrict__ outK,
                                          u16* __restrict__ outV, int blk0,
                                          u16* __restrict__ lds) {
  const int t = threadIdx.x, lane = t & 63, w = t >> 6, c = lane & 15, hi = lane >> 4;
  // ---- resident W slice: fb-frags w*G .. w*G+G-1, all 6 kk ----
  s16x8 wf[G][6];
#pragma unroll
  for (int f = 0; f < G; ++f)
#pragma unroll
    for (int kk = 0; kk < 6; ++kk)
      wf[f][kk] = ld_frag(&W[((size_t)(((w * G + f) * 6 + kk) * 64 + lane)) * 8]);
  // ---- staging geometry: thread covers row t>>4, 12 cols at (t&15)*12 ----
  const int srow = t >> 4, scol = (t & 15) * 12;
  float4 r0, r1, r2;
  auto ISSUE = [&](int i) {
    const float* src = A + (size_t)((blk0 * 8 + i) * 16 + srow) * 192 + scol;
    r0 = ((const float4*)src)[0];
    r1 = ((const float4*)src)[1];
    r2 = ((const float4*)src)[2];
  };
  auto WRITE = [&](int slot) {
    u16* sl = lds + slot * 3072;
#pragma unroll
    for (int j = 0; j < 3; ++j) {
      float4 v = (j == 0) ? r0 : (j == 1) ? r1 : r2;
      const int c0 = scol + j * 4, kk = c0 >> 5, rem = c0 & 31;
      const int h2 = rem >> 3, e0 = rem & 7;
      uint2 pv;
      pv.x = pk_bf16(v.x, v.y);
      pv.y = pk_bf16(v.z, v.w);
      *(uint2*)&sl[((kk << 6) + (h2 << 4) + srow) * 8 + e0] = pv;
    }
  };
  ISSUE(0); WRITE(0);                              // one-time stall, slot0
  ISSUE(1);                                        // tile1 in flight
  for (int i = 0; i < 8; ++i) {
    __syncthreads();                               // slot i%3 ready for all
    if (i + 1 < 8) WRITE((i + 1) % 3);             // regs from iter i-1: landed
    if (i + 2 < 8) ISSUE(i + 2);                   // 2-tile cover
    const u16* sl = lds + (i % 3) * 3072;
    s16x8 af[6];
#pragma unroll
    for (int kk = 0; kk < 6; ++kk)
      af[kk] = ld_frag(&sl[((kk << 6) + lane) << 3]);
    f32x4 acc[G];
#pragma unroll
    for (int f = 0; f < G; ++f) acc[f] = f32x4{0.f, 0.f, 0.f, 0.f};
#pragma unroll
    for (int kk = 0; kk < 6; ++kk)
#pragma unroll
      for (int f = 0; f < G; ++f)
        acc[f] = mfma16(wf[f][kk], af[kk], acc[f]);
    const int m = (blk0 * 8 + i) * 16 + c;
#pragma unroll
    for (int f = 0; f < G; ++f) {
      const int fb = ((w * G + f) << 4) + (hi << 2);
      uint2 pv;
      pv.x = pk_bf16(acc[f][0], acc[f][1]);
      pv.y = pk_bf16(acc[f][2], acc[f][3]);
      if (MODE == 0) {
        int b = m >> 8, q = m & 255, hh = fb >> 5, d = fb & 31;
        *(uint2*)&outQ[((((size_t)(b * 6 + hh)) << 8) + q) * 32 + d] = pv;
      } else {
        int b = m / 576, tok = m - b * 576;
        if (fb >= 192) {                           // V: layout unchanged
          int f2 = fb - 192, hh = f2 >> 5, d = f2 & 31;
          *(uint2*)&outV[(((size_t)(b * 6 + hh)) * 576 + tok) * 32 + d] = pv;
        } else {                                   // K: fragment-linear for attn
          int hh = fb >> 5, dd = fb & 31;
          int half = dd >> 4, uu = (dd >> 3) & 1, e0 = dd & 7;
          int ktt = tok >> 5, lt = tok & 31;
          *(uint2*)&outK[(size_t)((b * 6 + hh) * 18 + ktt) * 1024 +
                         half * 512 + uu * 256 + lt * 8 + e0] = pv;
        }
      }
    }
  }
}

__launch_bounds__(256, 2)
__global__ void proj_all(const float* __restrict__ xq, const float* __restrict__ xkv,
                         const u16* __restrict__ wqs, const u16* __restrict__ wkvs,
                         u16* __restrict__ Qws, u16* __restrict__ Kws,
                         u16* __restrict__ Vws) {
  __shared__ __align__(16) u16 lds[9216];          // 18,432 B: 3-slot A ring
  int blk = blockIdx.x;
  if (blk < 512) proj_body<3, 0>(xq, wqs, Qws, nullptr, nullptr, blk, lds);
  else           proj_body<6, 1>(xkv, wkvs, nullptr, Kws, Vws, blk - 512, lds);
}

// ---------------- kernel 4: fused attention ---------------------------------
// R8: REVERTED to the verified depth-2 pipeline. R7's depth-4 blew the VGPR
// budget (128-cap, live set ~190) -> ~860 MB scratch traffic (FETCH 400 MB /
// WRITE 648 MB vs 140/50 legit), 4x regression. Depth-2 fits in ~64 VGPR.
#define VSTR 600
__launch_bounds__(512)
__global__ void attn(const u16* __restrict__ Qws, const u16* __restrict__ Kws,
                     const u16* __restrict__ Vws, const u16* __restrict__ rpb,
                     float* __restrict__ out) {
  __shared__ __align__(16) u16 Vt[32 * VSTR];
  const int bh = blockIdx.x, b = bh / 6, h = bh - b * 6;
  const size_t kvbase = (size_t)bh * 576 * 32;     // V only
  const int t = threadIdx.x;
  for (int key = t; key < 576; key += 512) {       // stage V permuted (verified)
    int kk = key & 31, k15 = kk & 15;
    int p = ((kk >> 4) << 4) | (((k15 >> 2) & 1) << 3) | ((k15 >> 3) << 2) | (k15 & 3);
    int col = ((key >> 5) << 5) + p;
    const uint4* src = (const uint4*)&Vws[kvbase + (size_t)key * 32];
    uint4 r[4] = {src[0], src[1], src[2], src[3]};
    const u16* vs = (const u16*)r;
#pragma unroll
    for (int d = 0; d < 32; ++d) Vt[d * VSTR + col] = vs[d];
  }
  const int lane = t & 63, l31 = lane & 31, u = lane >> 5, w = t >> 6;
  const int qg = (w << 5) + l31;
  s16x8 qf[2];
#pragma unroll
  for (int m = 0; m < 2; ++m)
    qf[m] = ld_frag(&Qws[((size_t)bh * 256 + qg) * 32 + (m << 4) + (u << 3)]);
  __syncthreads();
  f32x16 oacc;
#pragma unroll
  for (int r = 0; r < 16; ++r) oacc[r] = 0.f;
  float psum = 0.f;
  // K fragment-linear: per kt, kA at kfb + kt*1024, kB at +512 (u16 units)
  const u16* kfb = Kws + (size_t)bh * 18432 + (size_t)lane * 8;
  // bias fragment-linear: per kt, 16 u16 at bp0 + kt*8192
  const u16* bp0 = rpb + (size_t)h * 147456 + (size_t)t * 16;
  s16x8 kA[2], kB[2];
  uint4 bA[2], bB[2];
  kA[0] = ld_frag(kfb);        kB[0] = ld_frag(kfb + 512);
  kA[1] = ld_frag(kfb + 1024); kB[1] = ld_frag(kfb + 1536);
  bA[0] = *(const uint4*)(bp0);        bB[0] = *(const uint4*)(bp0 + 8);
  bA[1] = *(const uint4*)(bp0 + 8192); bB[1] = *(const uint4*)(bp0 + 8192 + 8);
#pragma unroll 2
  for (int kt = 0; kt < 18; ++kt) {
    const int k0 = kt << 5, cur = kt & 1;          // cur compile-time (unroll 2)
    s16x8 vf0 = ld_frag(&Vt[l31 * VSTR + k0 + (u << 3)]);
    s16x8 vf1 = ld_frag(&Vt[l31 * VSTR + k0 + 16 + (u << 3)]);
    f32x16 st;
#pragma unroll
    for (int r = 0; r < 16; ++r) st[r] = 0.f;
    st = mfma32(kA[cur], qf[0], st);               // d = 0..15
    st = mfma32(kB[cur], qf[1], st);               // d = 16..31
    uint4 bAc = bA[cur], bBc = bB[cur];
    if (kt < 16) {                                 // prefetch kt+2
      kA[cur] = ld_frag(kfb + (size_t)(kt + 2) * 1024);
      kB[cur] = ld_frag(kfb + (size_t)(kt + 2) * 1024 + 512);
      bA[cur] = *(const uint4*)(bp0 + (size_t)(kt + 2) * 8192);
      bB[cur] = *(const uint4*)(bp0 + (size_t)(kt + 2) * 8192 + 8);
    }
    const u16* b0 = (const u16*)&bAc;
    const u16* b1 = (const u16*)&bBc;
    float e[16];
#pragma unroll
    for (int r = 0; r < 8; ++r)
      e[r] = EXP2(st[r] + bf2f(b0[r]));            // key-row = (r&3)+8(r>>2)+4u
#pragma unroll
    for (int r = 8; r < 16; ++r)
      e[r] = EXP2(st[r] + bf2f(b1[r - 8]));
    psum += (((e[0] + e[1]) + (e[2] + e[3])) + ((e[4] + e[5]) + (e[6] + e[7]))) +
            (((e[8] + e[9]) + (e[10] + e[11])) + ((e[12] + e[13]) + (e[14] + e[15])));
    uint4 pa, pb;
    pa.x = pk_bf16(e[0], e[1]);   pa.y = pk_bf16(e[2], e[3]);
    pa.z = pk_bf16(e[4], e[5]);   pa.w = pk_bf16(e[6], e[7]);
    pb.x = pk_bf16(e[8], e[9]);   pb.y = pk_bf16(e[10], e[11]);
    pb.z = pk_bf16(e[12], e[13]); pb.w = pk_bf16(e[14], e[15]);
    s16x8 pf0 = __builtin_bit_cast(s16x8, pa);
    s16x8 pf1 = __builtin_bit_cast(s16x8, pb);
    oacc = mfma32(vf0, pf0, oacc);
    oacc = mfma32(vf1, pf1, oacc);
  }
  float tot = psum + __shfl_xor(psum, 32);
  float rs = 1.0f / tot;
  float* op = out + ((size_t)b * 256 + qg) * 192 + h * 32 + (u << 2);
#pragma unroll
  for (int g = 0; g < 4; ++g) {
    float4 o;
    o.x = oacc[(g << 2) + 0] * rs; o.y = oacc[(g << 2) + 1] * rs;
    o.z = oacc[(g << 2) + 2] * rs; o.w = oacc[(g << 2) + 3] * rs;
    *(float4*)(op + (g << 3)) = o;
  }
}

// ---------------- launcher -------------------------------------------------
extern "C" void kernel_launch(void* const* d_in, const int* in_sizes, int n_in,
                              void* d_out, int out_size, void* d_ws, size_t ws_size,
                              hipStream_t stream) {
  const float* x_q   = (const float*)d_in[0];
  const float* x_kv  = (const float*)d_in[1];
  const int*   rpi   = (const int*)d_in[2];
  const float* Wq    = (const float*)d_in[3];
  const float* Wkv   = (const float*)d_in[4];
  const float* table = (const float*)d_in[5];
  float* out = (float*)d_out;

  char* ws = (char*)d_ws;
  u16* wqs  = (u16*)(ws);                          //    73,728 B (swizzled)
  u16* wkvs = (u16*)(ws + 73728);                  //   147,456 B (swizzled)
  u16* rpb  = (u16*)(ws + 221184);                 // 1,769,472 B  frag-order
  u16* Qws  = (u16*)(ws + 1990656);                // 25,165,824 B
  u16* Kws  = (u16*)(ws + 27156480);               // 56,623,104 B (frag-linear)
  u16* Vws  = (u16*)(ws + 83779584);               // 56,623,104 B  (total ~134 MB)

  prep_w<<<54, 256, 0, stream>>>(Wq, Wkv, wqs, wkvs);
  build_rpb<<<864, 64, 0, stream>>>(rpi, table, rpb);
  proj_all<<<1664, 256, 0, stream>>>(x_q, x_kv, wqs, wkvs, Qws, Kws, Vws);
  attn<<<1536, 512, 0, stream>>>(Qws, Kws, Vws, rpb, out);
}

// Round 9
// 337.033 us; speedup vs baseline: 1.9405x; 1.0006x over previous
//
#include <hip/hip_runtime.h>
#include <cstdint>

typedef unsigned short u16;
typedef short s16x8 __attribute__((ext_vector_type(8)));
typedef float f32x4 __attribute__((ext_vector_type(4)));
typedef float f32x16 __attribute__((ext_vector_type(16)));

#if __has_builtin(__builtin_amdgcn_exp2f)
#define EXP2(x) __builtin_amdgcn_exp2f(x)
#else
#define EXP2(x) __expf((x)*0.6931471805599453f)
#endif

__device__ __forceinline__ u16 f2bf(float x) {
  uint32_t u = __builtin_bit_cast(uint32_t, x);
  u += 0x7FFFu + ((u >> 16) & 1u);   // RTNE
  return (u16)(u >> 16);
}
__device__ __forceinline__ float bf2f(u16 v) {
  return __builtin_bit_cast(float, (uint32_t)v << 16);
}
__device__ __forceinline__ uint32_t pk_bf16(float lo, float hi) {
  uint32_t ul = __builtin_bit_cast(uint32_t, lo);
  uint32_t uh = __builtin_bit_cast(uint32_t, hi);
  ul += 0x7FFFu + ((ul >> 16) & 1u);
  uh += 0x7FFFu + ((uh >> 16) & 1u);
  return __builtin_amdgcn_perm(uh, ul, 0x07060302u);
}
__device__ __forceinline__ f32x4 mfma16(s16x8 a, s16x8 b, f32x4 c) {
  return __builtin_amdgcn_mfma_f32_16x16x32_bf16(a, b, c, 0, 0, 0);
}
__device__ __forceinline__ f32x16 mfma32(s16x8 a, s16x8 b, f32x16 c) {
  return __builtin_amdgcn_mfma_f32_32x32x16_bf16(a, b, c, 0, 0, 0);
}
__device__ __forceinline__ s16x8 ld_frag(const u16* p) {
  uint4 v = *(const uint4*)p;
  return __builtin_bit_cast(s16x8, v);
}

// ---------------- kernel 1: W fp32 -> bf16, MFMA-fragment-linear order -----
// Q scale = 1/sqrt(32) * log2(e)  (exp -> exp2 fold, see attn)
__global__ void prep_w(const float* __restrict__ Wq, const float* __restrict__ Wkv,
                       u16* __restrict__ wqs, u16* __restrict__ wkvs) {
  int tid = blockIdx.x * 256 + threadIdx.x;        // 0 .. 13823
  if (tid >= 13824) return;
  bool isQ = tid < 4608;                           // Q: 12 fb * 6 kk * 64 lanes
  int id = isQ ? tid : tid - 4608;                 // KV: 24 fb * 6 kk * 64 lanes
  int lane = id & 63, fk = id >> 6;
  int kk = fk % 6, fb = fk / 6;
  int f = fb * 16 + (lane & 15), k0 = kk * 32 + ((lane >> 4) << 3);
  const float* src = (isQ ? Wq : Wkv) + (size_t)f * 192 + k0;
  const float sc = isQ ? 0.2550348583f : 1.0f;     // (1/sqrt(32))*log2e
  float4 a = ((const float4*)src)[0], b = ((const float4*)src)[1];
  uint4 o;
  o.x = pk_bf16(a.x * sc, a.y * sc); o.y = pk_bf16(a.z * sc, a.w * sc);
  o.z = pk_bf16(b.x * sc, b.y * sc); o.w = pk_bf16(b.z * sc, b.w * sc);
  *(uint4*)&(isQ ? wqs : wkvs)[(size_t)id * 8] = o;
}

// ---------------- kernel 2: rpb in MFMA-C fragment order -------------------
// rpb4[h][kt][w][lane][r] = bf16(log2e * table[rpi[q][key]][h])
//   q = w*32 + (lane&31), key = kt*32 + (r&3) + 8*(r>>2) + 4*(lane>>5)
__global__ void build_rpb(const int* __restrict__ rpi, const float* __restrict__ table,
                          u16* __restrict__ rpb) {
  const int bi = blockIdx.x;                       // grid 864 = (6h*18kt) * 8w
  const int wv = bi & 7, hk = bi >> 3;
  const int h = hk / 18, kt = hk - h * 18;
  const int lane = threadIdx.x;                    // block 64
  const int u = lane >> 5, l31 = lane & 31;
  const int q = (wv << 5) + l31;
  const int n0 = (kt << 5) + (u << 2);             // + 8g gives the int4 base
  u16 vals[16];
#pragma unroll
  for (int g = 0; g < 4; ++g) {
    int4 id4 = *(const int4*)&rpi[q * 576 + n0 + (g << 3)];   // keys +0..3
    vals[(g << 2) + 0] = f2bf(table[id4.x * 6 + h] * 1.4426950409f);
    vals[(g << 2) + 1] = f2bf(table[id4.y * 6 + h] * 1.4426950409f);
    vals[(g << 2) + 2] = f2bf(table[id4.z * 6 + h] * 1.4426950409f);
    vals[(g << 2) + 3] = f2bf(table[id4.w * 6 + h] * 1.4426950409f);
  }
  uint4* dst = (uint4*)&rpb[((size_t)hk * 512 + (wv << 6) + lane) * 16];
  dst[0] = *(uint4*)&vals[0];
  dst[1] = *(uint4*)&vals[8];
}

// ---------------- kernel 3: W-STATIONARY projection GEMM -------------------
// R9: (a) PADDED frag-linear LDS: entry n = (kk*4+h2)*17 + row (was *16).
// Unpadded, write bank = f(row%8) only -> all 24 k-groups of a row on one
// bank pair -> 8-way ds_write serialization (R8: SQ_LDS_BANK_CONFLICT 4.47M,
// on the barrier critical path). Padded: n%8 = (kk*4+h2+row)%8 spreads writes
// over all banks (~2-way = free); frag ds_read_b128 keeps its optimal 8-cycle
// pattern. (b) 4 tiles/block, grid 3328: halves the serial tile chain, doubles
// blocks/CU available (attacks the 19% occupancy).
#define SLOT 3264                                  // u16 per slot: 408 * 8
template <int G, int MODE>
__device__ __forceinline__ void proj_body(const float* __restrict__ A,
                                          const u16* __restrict__ W,
                                          u16* __restrict__ outQ, u16* __restrict__ outK,
                                          u16* __restrict__ outV, int blk0,
                                          u16* __restrict__ lds) {
  const int t = threadIdx.x, lane = t & 63, w = t >> 6, c = lane & 15, hi = lane >> 4;
  // ---- resident W slice: fb-frags w*G .. w*G+G-1, all 6 kk ----
  s16x8 wf[G][6];
#pragma unroll
  for (int f = 0; f < G; ++f)
#pragma unroll
    for (int kk = 0; kk < 6; ++kk)
      wf[f][kk] = ld_frag(&W[((size_t)(((w * G + f) * 6 + kk) * 64 + lane)) * 8]);
  // ---- staging geometry: thread covers row t>>4, 12 cols at (t&15)*12 ----
  const int srow = t >> 4, scol = (t & 15) * 12;
  float4 r0, r1, r2;
  auto ISSUE = [&](int i) {
    const float* src = A + (size_t)((blk0 * 4 + i) * 16 + srow) * 192 + scol;
    r0 = ((const float4*)src)[0];
    r1 = ((const float4*)src)[1];
    r2 = ((const float4*)src)[2];
  };
  auto WRITE = [&](int slot) {
    u16* sl = lds + slot * SLOT;
#pragma unroll
    for (int j = 0; j < 3; ++j) {
      float4 v = (j == 0) ? r0 : (j == 1) ? r1 : r2;
      const int c0 = scol + j * 4, kk = c0 >> 5, rem = c0 & 31;
      const int h2 = rem >> 3, e0 = rem & 7;
      uint2 pv;
      pv.x = pk_bf16(v.x, v.y);
      pv.y = pk_bf16(v.z, v.w);
      *(uint2*)&sl[(((kk << 2) + h2) * 17 + srow) * 8 + e0] = pv;
    }
  };
  ISSUE(0); WRITE(0);                              // one-time stall, slot0
  ISSUE(1);                                        // tile1 in flight
  for (int i = 0; i < 4; ++i) {
    __syncthreads();                               // slot i%3 ready for all
    if (i + 1 < 4) WRITE((i + 1) % 3);             // regs from iter i-1: landed
    if (i + 2 < 4) ISSUE(i + 2);                   // 2-tile cover
    const u16* sl = lds + (i % 3) * SLOT;
    s16x8 af[6];
#pragma unroll
    for (int kk = 0; kk < 6; ++kk)
      af[kk] = ld_frag(&sl[(((kk << 2) + hi) * 17 + c) * 8]);
    f32x4 acc[G];
#pragma unroll
    for (int f = 0; f < G; ++f) acc[f] = f32x4{0.f, 0.f, 0.f, 0.f};
#pragma unroll
    for (int kk = 0; kk < 6; ++kk)
#pragma unroll
      for (int f = 0; f < G; ++f)
        acc[f] = mfma16(wf[f][kk], af[kk], acc[f]);
    const int m = (blk0 * 4 + i) * 16 + c;
#pragma unroll
    for (int f = 0; f < G; ++f) {
      const int fb = ((w * G + f) << 4) + (hi << 2);
      uint2 pv;
      pv.x = pk_bf16(acc[f][0], acc[f][1]);
      pv.y = pk_bf16(acc[f][2], acc[f][3]);
      if (MODE == 0) {
        int b = m >> 8, q = m & 255, hh = fb >> 5, d = fb & 31;
        *(uint2*)&outQ[((((size_t)(b * 6 + hh)) << 8) + q) * 32 + d] = pv;
      } else {
        int b = m / 576, tok = m - b * 576;
        if (fb >= 192) {                           // V: layout unchanged
          int f2 = fb - 192, hh = f2 >> 5, d = f2 & 31;
          *(uint2*)&outV[(((size_t)(b * 6 + hh)) * 576 + tok) * 32 + d] = pv;
        } else {                                   // K: fragment-linear for attn
          int hh = fb >> 5, dd = fb & 31;
          int half = dd >> 4, uu = (dd >> 3) & 1, e0 = dd & 7;
          int ktt = tok >> 5, lt = tok & 31;
          *(uint2*)&outK[(size_t)((b * 6 + hh) * 18 + ktt) * 1024 +
                         half * 512 + uu * 256 + lt * 8 + e0] = pv;
        }
      }
    }
  }
}

__launch_bounds__(256, 2)
__global__ void proj_all(const float* __restrict__ xq, const float* __restrict__ xkv,
                         const u16* __restrict__ wqs, const u16* __restrict__ wkvs,
                         u16* __restrict__ Qws, u16* __restrict__ Kws,
                         u16* __restrict__ Vws) {
  __shared__ __align__(16) u16 lds[3 * SLOT];      // 19,584 B: 3-slot A ring
  int blk = blockIdx.x;                            // grid 3328 = 1024 Q + 2304 KV
  if (blk < 1024) proj_body<3, 0>(xq, wqs, Qws, nullptr, nullptr, blk, lds);
  else            proj_body<6, 1>(xkv, wkvs, nullptr, Kws, Vws, blk - 1024, lds);
}

// ---------------- kernel 4: fused attention ---------------------------------
// Verified depth-2 pipeline (R8). R7's depth-4 spilled (VGPR cap 128, live
// ~190 -> 860 MB scratch). Depth-2 fits ~64 VGPR. FROZEN this round.
#define VSTR 600
__launch_bounds__(512)
__global__ void attn(const u16* __restrict__ Qws, const u16* __restrict__ Kws,
                     const u16* __restrict__ Vws, const u16* __restrict__ rpb,
                     float* __restrict__ out) {
  __shared__ __align__(16) u16 Vt[32 * VSTR];
  const int bh = blockIdx.x, b = bh / 6, h = bh - b * 6;
  const size_t kvbase = (size_t)bh * 576 * 32;     // V only
  const int t = threadIdx.x;
  for (int key = t; key < 576; key += 512) {       // stage V permuted (verified)
    int kk = key & 31, k15 = kk & 15;
    int p = ((kk >> 4) << 4) | (((k15 >> 2) & 1) << 3) | ((k15 >> 3) << 2) | (k15 & 3);
    int col = ((key >> 5) << 5) + p;
    const uint4* src = (const uint4*)&Vws[kvbase + (size_t)key * 32];
    uint4 r[4] = {src[0], src[1], src[2], src[3]};
    const u16* vs = (const u16*)r;
#pragma unroll
    for (int d = 0; d < 32; ++d) Vt[d * VSTR + col] = vs[d];
  }
  const int lane = t & 63, l31 = lane & 31, u = lane >> 5, w = t >> 6;
  const int qg = (w << 5) + l31;
  s16x8 qf[2];
#pragma unroll
  for (int m = 0; m < 2; ++m)
    qf[m] = ld_frag(&Qws[((size_t)bh * 256 + qg) * 32 + (m << 4) + (u << 3)]);
  __syncthreads();
  f32x16 oacc;
#pragma unroll
  for (int r = 0; r < 16; ++r) oacc[r] = 0.f;
  float psum = 0.f;
  // K fragment-linear: per kt, kA at kfb + kt*1024, kB at +512 (u16 units)
  const u16* kfb = Kws + (size_t)bh * 18432 + (size_t)lane * 8;
  // bias fragment-linear: per kt, 16 u16 at bp0 + kt*8192
  const u16* bp0 = rpb + (size_t)h * 147456 + (size_t)t * 16;
  s16x8 kA[2], kB[2];
  uint4 bA[2], bB[2];
  kA[0] = ld_frag(kfb);        kB[0] = ld_frag(kfb + 512);
  kA[1] = ld_frag(kfb + 1024); kB[1] = ld_frag(kfb + 1536);
  bA[0] = *(const uint4*)(bp0);        bB[0] = *(const uint4*)(bp0 + 8);
  bA[1] = *(const uint4*)(bp0 + 8192); bB[1] = *(const uint4*)(bp0 + 8192 + 8);
#pragma unroll 2
  for (int kt = 0; kt < 18; ++kt) {
    const int k0 = kt << 5, cur = kt & 1;          // cur compile-time (unroll 2)
    s16x8 vf0 = ld_frag(&Vt[l31 * VSTR + k0 + (u << 3)]);
    s16x8 vf1 = ld_frag(&Vt[l31 * VSTR + k0 + 16 + (u << 3)]);
    f32x16 st;
#pragma unroll
    for (int r = 0; r < 16; ++r) st[r] = 0.f;
    st = mfma32(kA[cur], qf[0], st);               // d = 0..15
    st = mfma32(kB[cur], qf[1], st);               // d = 16..31
    uint4 bAc = bA[cur], bBc = bB[cur];
    if (kt < 16) {                                 // prefetch kt+2
      kA[cur] = ld_frag(kfb + (size_t)(kt + 2) * 1024);
      kB[cur] = ld_frag(kfb + (size_t)(kt + 2) * 1024 + 512);
      bA[cur] = *(const uint4*)(bp0 + (size_t)(kt + 2) * 8192);
      bB[cur] = *(const uint4*)(bp0 + (size_t)(kt + 2) * 8192 + 8);
    }
    const u16* b0 = (const u16*)&bAc;
    const u16* b1 = (const u16*)&bBc;
    float e[16];
#pragma unroll
    for (int r = 0; r < 8; ++r)
      e[r] = EXP2(st[r] + bf2f(b0[r]));            // key-row = (r&3)+8(r>>2)+4u
#pragma unroll
    for (int r = 8; r < 16; ++r)
      e[r] = EXP2(st[r] + bf2f(b1[r - 8]));
    psum += (((e[0] + e[1]) + (e[2] + e[3])) + ((e[4] + e[5]) + (e[6] + e[7]))) +
            (((e[8] + e[9]) + (e[10] + e[11])) + ((e[12] + e[13]) + (e[14] + e[15])));
    uint4 pa, pb;
    pa.x = pk_bf16(e[0], e[1]);   pa.y = pk_bf16(e[2], e[3]);
    pa.z = pk_bf16(e[4], e[5]);   pa.w = pk_bf16(e[6], e[7]);
    pb.x = pk_bf16(e[8], e[9]);   pb.y = pk_bf16(e[10], e[11]);
    pb.z = pk_bf16(e[12], e[13]); pb.w = pk_bf16(e[14], e[15]);
    s16x8 pf0 = __builtin_bit_cast(s16x8, pa);
    s16x8 pf1 = __builtin_bit_cast(s16x8, pb);
    oacc = mfma32(vf0, pf0, oacc);
    oacc = mfma32(vf1, pf1, oacc);
  }
  float tot = psum + __shfl_xor(psum, 32);
  float rs = 1.0f / tot;
  float* op = out + ((size_t)b * 256 + qg) * 192 + h * 32 + (u << 2);
#pragma unroll
  for (int g = 0; g < 4; ++g) {
    float4 o;
    o.x = oacc[(g << 2) + 0] * rs; o.y = oacc[(g << 2) + 1] * rs;
    o.z = oacc[(g << 2) + 2] * rs; o.w = oacc[(g << 2) + 3] * rs;
    *(float4*)(op + (g << 3)) = o;
  }
}

// ---------------- launcher -------------------------------------------------
extern "C" void kernel_launch(void* const* d_in, const int* in_sizes, int n_in,
                              void* d_out, int out_size, void* d_ws, size_t ws_size,
                              hipStream_t stream) {
  const float* x_q   = (const float*)d_in[0];
  const float* x_kv  = (const float*)d_in[1];
  const int*   rpi   = (const int*)d_in[2];
  const float* Wq    = (const float*)d_in[3];
  const float* Wkv   = (const float*)d_in[4];
  const float* table = (const float*)d_in[5];
  float* out = (float*)d_out;

  char* ws = (char*)d_ws;
  u16* wqs  = (u16*)(ws);                          //    73,728 B (swizzled)
  u16* wkvs = (u16*)(ws + 73728);                  //   147,456 B (swizzled)
  u16* rpb  = (u16*)(ws + 221184);                 // 1,769,472 B  frag-order
  u16* Qws  = (u16*)(ws + 1990656);                // 25,165,824 B
  u16* Kws  = (u16*)(ws + 27156480);               // 56,623,104 B (frag-linear)
  u16* Vws  = (u16*)(ws + 83779584);               // 56,623,104 B  (total ~134 MB)

  prep_w<<<54, 256, 0, stream>>>(Wq, Wkv, wqs, wkvs);
  build_rpb<<<864, 64, 0, stream>>>(rpi, table, rpb);
  proj_all<<<3328, 256, 0, stream>>>(x_q, x_kv, wqs, wkvs, Qws, Kws, Vws);
  attn<<<1536, 512, 0, stream>>>(Qws, Kws, Vws, rpb, out);
}